// Round 10
// baseline (175.318 us; speedup 1.0000x reference)
//
#include <hip/hip_runtime.h>
#include <hip/hip_bf16.h>

#define B_    1024
#define N_    128
#define FEAT_ 512
#define HID_  256

typedef __bf16 bf16x8 __attribute__((ext_vector_type(8)));
typedef float  f32x4  __attribute__((ext_vector_type(4)));

__device__ __forceinline__ unsigned int f2bf(float f) {
    unsigned int u = __float_as_uint(f);
    u += 0x7fffu + ((u >> 16) & 1u);   // round-to-nearest-even
    return u >> 16;
}
__device__ __forceinline__ unsigned int pack2(float a, float b) {
    return f2bf(a) | (f2bf(b) << 16);
}

// ---------------- prep: proj-partial (blocks 0..1023) + conv (blocks 1024..3071) ----------------
// proj-partial: block=(f-chunk c of 128, 4-row group). Thread=(r=t&3, h0=(t>>2)*4).
//   Writes pproj[c][row][h] fp32. 1024 blocks -> ~4/CU co-resident => load latency
//   hidden by TLP (R6-R8 lesson: the compiler won't give deep ILP; use TLP).
// conv: block=(n, 16-row group). Loads hoisted, convert + swizzled uint4 store
//   elem(j,k) -> j*256 + ((k>>3)^((j&7)<<2))*8 + (k&7).
//   v2[j]=2*sum_k mu_k M[j,k] via LDS sv[16][33]; cpart[n*16+jg] partial of mu'Mmu.
// block 0 / t 0 seeds out[0] with the clip residue (dist atomically adds the loss).
__global__ __launch_bounds__(256) void prep_kernel(
    const float* __restrict__ x, const float* __restrict__ W,
    const float* __restrict__ bias, const float* __restrict__ means,
    const float* __restrict__ invcov,
    float* __restrict__ pproj, unsigned short* __restrict__ Mbf,
    float* __restrict__ v2, float* __restrict__ cpart, float* __restrict__ out)
{
    const int t = threadIdx.x;
    if (blockIdx.x < 1024) {
        // ---------------- proj-partial role ----------------
        if (blockIdx.x == 0 && t == 0) out[0] = (float)(N_ - 1) * 1e-12f;  // loss seed
        const int c   = blockIdx.x & 3;         // f-chunk: f in [c*128, c*128+128)
        const int g   = blockIdx.x >> 2;        // 4-row group 0..255
        const int r   = t & 3;
        const int h0  = (t >> 2) * 4;           // output cols h0..h0+3
        const int row = g * 4 + r;
        const float* xr = x + (size_t)row * FEAT_ + c * 128;
        const float* Wc = W + (size_t)c * 128 * HID_;
        float4 acc = make_float4(0.f, 0.f, 0.f, 0.f);
        if (c == 0) acc = *(const float4*)(bias + h0);   // bias folded into chunk 0
        #pragma unroll 4
        for (int f = 0; f < 128; f += 4) {
            const float4 xv = *(const float4*)(xr + f);                       // per-lane VMEM
            const float4 w0 = *(const float4*)(Wc + (size_t)(f + 0) * HID_ + h0);
            const float4 w1 = *(const float4*)(Wc + (size_t)(f + 1) * HID_ + h0);
            const float4 w2 = *(const float4*)(Wc + (size_t)(f + 2) * HID_ + h0);
            const float4 w3 = *(const float4*)(Wc + (size_t)(f + 3) * HID_ + h0);
            acc.x += xv.x * w0.x + xv.y * w1.x + xv.z * w2.x + xv.w * w3.x;
            acc.y += xv.x * w0.y + xv.y * w1.y + xv.z * w2.y + xv.w * w3.y;
            acc.z += xv.x * w0.z + xv.y * w1.z + xv.z * w2.z + xv.w * w3.z;
            acc.w += xv.x * w0.w + xv.y * w1.w + xv.z * w2.w + xv.w * w3.w;
        }
        *(float4*)(pproj + (size_t)c * (B_ * HID_) + (size_t)row * HID_ + h0) = acc;
    } else {
        // ---------------- conv role ----------------
        __shared__ float sv[16][33];
        __shared__ float sw[2];
        const int cb = blockIdx.x - 1024;  // 0..2047
        const int n  = cb >> 4;            // 0..127
        const int jg = cb & 15;            // 16-row group
        const float* Mn = invcov + (size_t)n * (HID_ * HID_) + (size_t)jg * 16 * HID_;
        const float* mu = means + (size_t)n * HID_;
        unsigned short* Mb = Mbf + (size_t)n * (HID_ * HID_) + (size_t)jg * 16 * HID_;
        const int gc = t & 31;             // granule column (k = gc*8 .. gc*8+7)
        const int r0 = t >> 5;             // rows r0 and r0+8
        // hoist ALL loads so they are in flight together
        const float* s0 = Mn + (size_t)r0 * HID_ + gc * 8;
        const float* s1 = Mn + (size_t)(r0 + 8) * HID_ + gc * 8;
        const float4 a0 = *(const float4*)s0;
        const float4 b0 = *(const float4*)(s0 + 4);
        const float4 a1 = *(const float4*)s1;
        const float4 b1 = *(const float4*)(s1 + 4);
        const float4 mk0 = *(const float4*)(mu + gc * 8);
        const float4 mk1 = *(const float4*)(mu + gc * 8 + 4);
        const int g20 = gc ^ ((r0 & 7) << 2);
        const int g21 = gc ^ (((r0 + 8) & 7) << 2);
        *(uint4*)(Mb + (size_t)r0 * HID_ + g20 * 8) =
            make_uint4(pack2(a0.x, a0.y), pack2(a0.z, a0.w), pack2(b0.x, b0.y), pack2(b0.z, b0.w));
        *(uint4*)(Mb + (size_t)(r0 + 8) * HID_ + g21 * 8) =
            make_uint4(pack2(a1.x, a1.y), pack2(a1.z, a1.w), pack2(b1.x, b1.y), pack2(b1.z, b1.w));
        sv[r0][gc]     = a0.x * mk0.x + a0.y * mk0.y + a0.z * mk0.z + a0.w * mk0.w
                       + b0.x * mk1.x + b0.y * mk1.y + b0.z * mk1.z + b0.w * mk1.w;
        sv[r0 + 8][gc] = a1.x * mk0.x + a1.y * mk0.y + a1.z * mk0.z + a1.w * mk0.w
                       + b1.x * mk1.x + b1.y * mk1.y + b1.z * mk1.z + b1.w * mk1.w;
        __syncthreads();
        if (t < 128) {
            const int row = t >> 3;        // 0..15 (8 rows per wave)
            const int i0  = (t & 7) * 4;
            float v = sv[row][i0] + sv[row][i0 + 1] + sv[row][i0 + 2] + sv[row][i0 + 3];
            v += __shfl_xor(v, 1);         // reduce the 8 gc-groups (lane bits 0..2)
            v += __shfl_xor(v, 2);
            v += __shfl_xor(v, 4);
            const int j = jg * 16 + row;
            if ((t & 7) == 0) v2[(size_t)n * HID_ + j] = 2.f * v;
            float cc = ((t & 7) == 0) ? v * mu[j] : 0.f;
            cc += __shfl_xor(cc, 8);       // sum the 8 rows of this wave
            cc += __shfl_xor(cc, 16);
            cc += __shfl_xor(cc, 32);
            if ((t & 63) == 0) sw[t >> 6] = cc;
        }
        __syncthreads();
        if (t == 0) cpart[cb] = sw[0] + sw[1];
    }
}

// ---------------- projsum: xp = sum of 4 f-chunk partials; xbf = bf16(xp) ----------------
__global__ __launch_bounds__(256) void projsum_kernel(
    const float* __restrict__ pproj, float* __restrict__ xp,
    unsigned short* __restrict__ xbf)
{
    const int i = blockIdx.x * 256 + threadIdx.x;   // float4 index 0..65535
    const float4 a = ((const float4*)pproj)[i];
    const float4 b = ((const float4*)pproj)[i +  65536];
    const float4 c = ((const float4*)pproj)[i + 131072];
    const float4 d = ((const float4*)pproj)[i + 196608];
    float4 s;
    s.x = (a.x + b.x) + (c.x + d.x);
    s.y = (a.y + b.y) + (c.y + d.y);
    s.z = (a.z + b.z) + (c.z + d.z);
    s.w = (a.w + b.w) + (c.w + d.w);
    ((float4*)xp)[i] = s;
    ((uint2*)xbf)[i] = make_uint2(pack2(s.x, s.y), pack2(s.z, s.w));
}

// ---------------- dist (fused): distmat + loss, full j-range, pipelined LDS ----------------
// grid (4 bg, 128 n) = 512 blocks, 512 threads, 64 KB LDS (2 x 32 KB dbuf) -> 2 blocks/CU.
// 4 phases of 64 M-rows: DMA quarter p+1 (global_load_lds, pre-swizzled bf16) overlaps
// compute on quarter p; barrier per phase. dist^2 = sum_j (T - v2)_j * x_j + mu'Mmu;
// epilogue: sqrt + distmat store + labels-gather + one atomicAdd per wave into out[0].
__global__ __launch_bounds__(512, 4) void dist_kernel(
    const float* __restrict__ xp, const unsigned short* __restrict__ xbf,
    const unsigned short* __restrict__ Mbf, const float* __restrict__ v2,
    const float* __restrict__ cpart, const int* __restrict__ labels,
    float* __restrict__ out)
{
    extern __shared__ unsigned short Ms[];   // [2][64 rows][256 el] = 65536 B

    const int tid  = threadIdx.x;
    const int bh   = blockIdx.x;       // 0..3
    const int n    = blockIdx.y;       // 0..127
    const int wave = tid >> 6;
    const int lane = tid & 63;
    const int q    = lane >> 4;        // quad 0..3
    const int l    = lane & 15;

    const unsigned short* src = Mbf + (size_t)n * (HID_ * HID_);

    // ---- issue DMA for quarter 0 into buf 0 (overlaps afrag/cn setup) ----
    #pragma unroll
    for (int i = 0; i < 4; ++i) {
        const int c = wave * 4 + i;    // chunk 0..31, wave-uniform
        __builtin_amdgcn_global_load_lds(
            (const __attribute__((address_space(1))) unsigned int*)(src + (size_t)c * 512 + lane * 8),
            (__attribute__((address_space(3))) unsigned int*)&Ms[c * 512],
            16, 0, 0);
    }

    // ---- afrag: x rows (bf16, pre-converted), full K, 2 row-blocks of 16 ----
    // A layout: A[m=lane&15][k=quad*8+j]
    bf16x8 afrag[2][8];
    #pragma unroll
    for (int rb = 0; rb < 2; ++rb) {
        const unsigned short* xr = xbf + (size_t)(bh * 256 + wave * 32 + rb * 16 + l) * HID_;
        #pragma unroll
        for (int kk = 0; kk < 8; ++kk)
            afrag[rb][kk] = *(const bf16x8*)(xr + kk * 32 + q * 8);
    }
    // c_n = mu' M mu (block-uniform)
    float cn = 0.f;
    #pragma unroll
    for (int g = 0; g < 16; ++g) cn += cpart[n * 16 + g];

    __syncthreads();   // drains quarter-0 DMA

    float part[8];
    #pragma unroll
    for (int i = 0; i < 8; ++i) part[i] = 0.f;

    // epilogue x source: row (bh*256 + wave*32 + q*4 + r + rb*16), col (ct*16 + l)
    const size_t xbase = (size_t)(bh * 256 + wave * 32 + q * 4) * HID_ + l;

    #pragma unroll
    for (int p = 0; p < 4; ++p) {
        // prefetch quarter p+1 into the other buffer (overlaps this phase's compute)
        if (p < 3) {
            const unsigned short* sq = src + (size_t)(p + 1) * 16384;
            unsigned short* dq = &Ms[((p + 1) & 1) * 16384];
            #pragma unroll
            for (int i = 0; i < 4; ++i) {
                const int c = wave * 4 + i;
                __builtin_amdgcn_global_load_lds(
                    (const __attribute__((address_space(1))) unsigned int*)(sq + (size_t)c * 512 + lane * 8),
                    (__attribute__((address_space(3))) unsigned int*)(dq + c * 512),
                    16, 0, 0);
            }
        }
        const unsigned short* buf = &Ms[(p & 1) * 16384];
        #pragma unroll
        for (int ct2 = 0; ct2 < 4; ++ct2) {
            const int ct = p * 4 + ct2;            // 0..15, j-tile = ct*16..ct*16+15
            // hoist per-lane v2 + fp32 x loads ahead of the MFMA burst
            const float vv = v2[(size_t)n * HID_ + ct * 16 + l];
            float xl[8];
            #pragma unroll
            for (int rb = 0; rb < 2; ++rb)
                #pragma unroll
                for (int r = 0; r < 4; ++r)
                    xl[rb * 4 + r] = xp[xbase + (size_t)(rb * 16 + r) * HID_ + ct * 16];

            f32x4 acc0 = {0.f,0.f,0.f,0.f}, acc1 = {0.f,0.f,0.f,0.f};
            #pragma unroll
            for (int kk = 0; kk < 8; ++kk) {
                // row-in-buf jr=ct2*16+l; granule (kk*4+q)^((l&7)<<2) -> 2-way banks (free)
                const bf16x8 bfrag = *(const bf16x8*)&buf[(ct2 * 16 + l) * HID_ +
                                                          (((kk * 4 + q) ^ ((l & 7) << 2)) << 3)];
                acc0 = __builtin_amdgcn_mfma_f32_16x16x32_bf16(afrag[0][kk], bfrag, acc0, 0, 0, 0);
                acc1 = __builtin_amdgcn_mfma_f32_16x16x32_bf16(afrag[1][kk], bfrag, acc1, 0, 0, 0);
            }
            // fused: part += (T - v2) * x   (C/D layout: col=lane&15, row=quad*4+reg)
            #pragma unroll
            for (int r = 0; r < 4; ++r) {
                part[r]     += (acc0[r] - vv) * xl[r];
                part[4 + r] += (acc1[r] - vv) * xl[4 + r];
            }
        }
        __syncthreads();   // guards buf reuse + drains the prefetch
    }

    // reduce across the 16 col-lanes of each quad; epilogue: sqrt + store + loss gather
    #pragma unroll
    for (int i = 0; i < 8; ++i) {
        float v = part[i];
        v += __shfl_xor(v, 1);
        v += __shfl_xor(v, 2);
        v += __shfl_xor(v, 4);
        v += __shfl_xor(v, 8);
        part[i] = v;
    }
    float c = 0.f;
    if (l == 0) {
        #pragma unroll
        for (int i = 0; i < 8; ++i) {
            const int row = bh * 256 + wave * 32 + (i >> 2) * 16 + q * 4 + (i & 3);
            const float d = sqrtf(part[i] + cn + 1e-12f);
            out[1 + (size_t)row * N_ + n] = d;
            if (labels[row] == n) c += d;
        }
    }
    c += __shfl_xor(c, 16);   // combine the 4 l==0 lanes (0,16,32,48)
    c += __shfl_xor(c, 32);
    if (lane == 0 && c != 0.f) atomicAdd(out, c * (1.f / (float)B_));
}

extern "C" void kernel_launch(void* const* d_in, const int* in_sizes, int n_in,
                              void* d_out, int out_size, void* d_ws, size_t ws_size,
                              hipStream_t stream) {
    const float* x      = (const float*)d_in[0];
    const int*   labels = (const int*)d_in[1];
    const float* W      = (const float*)d_in[2];
    const float* bias   = (const float*)d_in[3];
    const float* means  = (const float*)d_in[4];
    const float* invcov = (const float*)d_in[5];
    float* out = (float*)d_out;

    // workspace carve-up (~22.7 MB total)
    char* ws = (char*)d_ws;
    unsigned short* Mbf   = (unsigned short*)(ws);               // 16,777,216 B
    float*          xp    = (float*)         (ws + 16777216);    //  1,048,576 B
    unsigned short* xbf   = (unsigned short*)(ws + 17825792);    //    524,288 B
    float*          v2    = (float*)         (ws + 18350080);    //    131,072 B
    float*          cpart = (float*)         (ws + 18481152);    //      8,192 B
    float*          pproj = (float*)         (ws + 18489344);    //  4,194,304 B

    constexpr int DIST_LDS = 2 * 64 * HID_ * 2;   // 65536 B dynamic LDS (2 x 32 KB)
    (void)hipFuncSetAttribute((const void*)dist_kernel,
                              hipFuncAttributeMaxDynamicSharedMemorySize, DIST_LDS);

    prep_kernel<<<dim3(3072), 256, 0, stream>>>(x, W, bias, means, invcov,
                                                pproj, Mbf, v2, cpart, out);
    projsum_kernel<<<dim3(256), 256, 0, stream>>>(pproj, xp, xbf);
    dist_kernel<<<dim3(4, N_), 512, DIST_LDS, stream>>>(xp, xbf, Mbf, v2, cpart,
                                                        labels, out);
}

// Round 11
// 161.532 us; speedup vs baseline: 1.0853x; 1.0853x over previous
//
#include <hip/hip_runtime.h>
#include <hip/hip_bf16.h>

#define B_    1024
#define N_    128
#define FEAT_ 512
#define HID_  256

typedef __bf16 bf16x8 __attribute__((ext_vector_type(8)));
typedef float  f32x4  __attribute__((ext_vector_type(4)));

__device__ __forceinline__ unsigned int f2bf(float f) {
    unsigned int u = __float_as_uint(f);
    u += 0x7fffu + ((u >> 16) & 1u);   // round-to-nearest-even
    return u >> 16;
}
__device__ __forceinline__ unsigned int pack2(float a, float b) {
    return f2bf(a) | (f2bf(b) << 16);
}
__device__ __forceinline__ float bcast(float v, int lane) {
    // wave-uniform broadcast from a VGPR: v_readlane -> SGPR (no LDS pipe, no s_load)
    return __uint_as_float(__builtin_amdgcn_readlane(__float_as_uint(v), lane));
}

// ---------------- prep: proj (blocks 0..255) + conv (blocks 256..2303) ----------------
// proj: 4 rows/block, t=h. Each lane holds 8 floats of each of the 4 x-rows
//   (8 coalesced float4 loads); inner loop broadcasts x[r][f] via v_readlane
//   (R6's LDS-broadcast burned ~8K wave-level ds_read_b32/block on the LDS pipe;
//   R7/R8's variants hit s_load / scheduling walls). W reads coalesced, L2-resident.
// conv: block=(n, 16-row group). Loads hoisted, convert + swizzled uint4 store
//   elem(j,k) -> j*256 + ((k>>3)^((j&7)<<2))*8 + (k&7).
//   v2[j]=2*sum_k mu_k M[j,k] via LDS sv[16][33]; cpart[n*16+jg] partial of mu'Mmu.
// proj block 0 / t 0 seeds out[0] with the clip residue (finalize atomically adds).
__global__ __launch_bounds__(256) void prep_kernel(
    const float* __restrict__ x, const float* __restrict__ W,
    const float* __restrict__ bias, const float* __restrict__ means,
    const float* __restrict__ invcov,
    float* __restrict__ xp, unsigned short* __restrict__ xbf,
    unsigned short* __restrict__ Mbf, float* __restrict__ v2,
    float* __restrict__ cpart, float* __restrict__ out)
{
    const int t = threadIdx.x;
    if (blockIdx.x < 256) {
        // ---------------- proj role ----------------
        if (blockIdx.x == 0 && t == 0) out[0] = (float)(N_ - 1) * 1e-12f;  // loss seed
        const int b0   = blockIdx.x * 4;
        const int h    = t;                 // output col 0..255
        const int lane = t & 63;
        // stage the 4 x-rows across the wave: lane holds f in [lane*8, lane*8+8)
        float xr[4][8];
        #pragma unroll
        for (int r = 0; r < 4; ++r) {
            const float4 a = *(const float4*)(x + (size_t)(b0 + r) * FEAT_ + lane * 8);
            const float4 b = *(const float4*)(x + (size_t)(b0 + r) * FEAT_ + lane * 8 + 4);
            xr[r][0] = a.x; xr[r][1] = a.y; xr[r][2] = a.z; xr[r][3] = a.w;
            xr[r][4] = b.x; xr[r][5] = b.y; xr[r][6] = b.z; xr[r][7] = b.w;
        }
        const float bb = bias[h];
        float acc[4] = {bb, bb, bb, bb};
        for (int fo = 0; fo < 64; ++fo) {       // src lane = fo, covers f = fo*8..fo*8+7
            float w[8];
            #pragma unroll
            for (int j = 0; j < 8; ++j)
                w[j] = W[(size_t)(fo * 8 + j) * HID_ + h];    // coalesced, L2-resident
            #pragma unroll
            for (int j = 0; j < 8; ++j) {
                #pragma unroll
                for (int r = 0; r < 4; ++r)
                    acc[r] += bcast(xr[r][j], fo) * w[j];
            }
        }
        #pragma unroll
        for (int r = 0; r < 4; ++r) {
            xp [(size_t)(b0 + r) * HID_ + h] = acc[r];
            xbf[(size_t)(b0 + r) * HID_ + h] = (unsigned short)f2bf(acc[r]);
        }
    } else {
        // ---------------- conv role ----------------
        __shared__ float sv[16][33];
        __shared__ float sw[2];
        const int cb = blockIdx.x - 256;   // 0..2047
        const int n  = cb >> 4;            // 0..127
        const int jg = cb & 15;            // 16-row group
        const float* Mn = invcov + (size_t)n * (HID_ * HID_) + (size_t)jg * 16 * HID_;
        const float* mu = means + (size_t)n * HID_;
        unsigned short* Mb = Mbf + (size_t)n * (HID_ * HID_) + (size_t)jg * 16 * HID_;
        const int gc = t & 31;             // granule column (k = gc*8 .. gc*8+7)
        const int r0 = t >> 5;             // rows r0 and r0+8
        // hoist ALL loads so they are in flight together
        const float* s0 = Mn + (size_t)r0 * HID_ + gc * 8;
        const float* s1 = Mn + (size_t)(r0 + 8) * HID_ + gc * 8;
        const float4 a0 = *(const float4*)s0;
        const float4 b0 = *(const float4*)(s0 + 4);
        const float4 a1 = *(const float4*)s1;
        const float4 b1 = *(const float4*)(s1 + 4);
        const float4 mk0 = *(const float4*)(mu + gc * 8);
        const float4 mk1 = *(const float4*)(mu + gc * 8 + 4);
        const int g20 = gc ^ ((r0 & 7) << 2);
        const int g21 = gc ^ (((r0 + 8) & 7) << 2);
        *(uint4*)(Mb + (size_t)r0 * HID_ + g20 * 8) =
            make_uint4(pack2(a0.x, a0.y), pack2(a0.z, a0.w), pack2(b0.x, b0.y), pack2(b0.z, b0.w));
        *(uint4*)(Mb + (size_t)(r0 + 8) * HID_ + g21 * 8) =
            make_uint4(pack2(a1.x, a1.y), pack2(a1.z, a1.w), pack2(b1.x, b1.y), pack2(b1.z, b1.w));
        sv[r0][gc]     = a0.x * mk0.x + a0.y * mk0.y + a0.z * mk0.z + a0.w * mk0.w
                       + b0.x * mk1.x + b0.y * mk1.y + b0.z * mk1.z + b0.w * mk1.w;
        sv[r0 + 8][gc] = a1.x * mk0.x + a1.y * mk0.y + a1.z * mk0.z + a1.w * mk0.w
                       + b1.x * mk1.x + b1.y * mk1.y + b1.z * mk1.z + b1.w * mk1.w;
        __syncthreads();
        if (t < 128) {
            const int row = t >> 3;        // 0..15 (8 rows per wave)
            const int i0  = (t & 7) * 4;
            float v = sv[row][i0] + sv[row][i0 + 1] + sv[row][i0 + 2] + sv[row][i0 + 3];
            v += __shfl_xor(v, 1);         // reduce the 8 gc-groups (lane bits 0..2)
            v += __shfl_xor(v, 2);
            v += __shfl_xor(v, 4);
            const int j = jg * 16 + row;
            if ((t & 7) == 0) v2[(size_t)n * HID_ + j] = 2.f * v;
            float cc = ((t & 7) == 0) ? v * mu[j] : 0.f;
            cc += __shfl_xor(cc, 8);       // sum the 8 rows of this wave
            cc += __shfl_xor(cc, 16);
            cc += __shfl_xor(cc, 32);
            if ((t & 63) == 0) sw[t >> 6] = cc;
        }
        __syncthreads();
        if (t == 0) cpart[cb] = sw[0] + sw[1];
    }
}

// ---------------- dist: p[jh][b][n] = sum_{j in half} (T[b,j] - v2[n,j]) * xp[b,j] ----------------
// T = x . M_n (bf16 MFMA, fp32 acc). grid (4 bg, 2 jh, 128 n) = 1024 blocks,
// 512 threads, 64 KB LDS -> 2 blocks/CU. M-half staged by pure global_load_lds DMA
// (pre-converted, pre-swizzled bf16). Wave owns 32 b-rows; afrag resident in 64 regs;
// per ct: 8 ds_read_b128 (2-way banks only) + 16 MFMA.  [R10 lesson: the fused
// single-n variant scattered 4-B column stores to out -> 62 MB HBM writes; keep the
// split p-buffer + coalesced finalize.]
__global__ __launch_bounds__(512, 4) void dist_kernel(
    const float* __restrict__ xp, const unsigned short* __restrict__ xbf,
    const unsigned short* __restrict__ Mbf, const float* __restrict__ v2,
    float* __restrict__ p)
{
    extern __shared__ unsigned short Ms[];   // 128 rows x 256 el (swizzled) = 65536 B

    const int tid  = threadIdx.x;
    const int bh   = blockIdx.x;       // 0..3
    const int jh   = blockIdx.y;       // 0..1
    const int n    = blockIdx.z;       // 0..127
    const int wave = tid >> 6;
    const int lane = tid & 63;
    const int q    = lane >> 4;        // quad 0..3
    const int l    = lane & 15;

    // ---- DMA stage 64 KB M-half: 64 chunks of 1 KB (wave, iter) ----
    const unsigned short* src = Mbf + (size_t)n * (HID_ * HID_) + (size_t)jh * 32768;
    #pragma unroll
    for (int i = 0; i < 8; ++i) {
        const int c = i * 8 + wave;    // chunk id, wave-uniform
        __builtin_amdgcn_global_load_lds(
            (const __attribute__((address_space(1))) unsigned int*)(src + (size_t)c * 512 + lane * 8),
            (__attribute__((address_space(3))) unsigned int*)&Ms[c * 512],
            16, 0, 0);
    }

    // ---- afrag: x rows (bf16, pre-converted), full K, 2 row-blocks of 16 ----
    // A layout: A[m=lane&15][k=quad*8+j]
    bf16x8 afrag[2][8];
    #pragma unroll
    for (int rb = 0; rb < 2; ++rb) {
        const unsigned short* xr = xbf + (size_t)(bh * 256 + wave * 32 + rb * 16 + l) * HID_;
        #pragma unroll
        for (int kk = 0; kk < 8; ++kk)
            afrag[rb][kk] = *(const bf16x8*)(xr + kk * 32 + q * 8);
    }
    // v2 per lane per ct (j = jh*128 + ct*16 + l)
    float v2l[8];
    #pragma unroll
    for (int ct = 0; ct < 8; ++ct)
        v2l[ct] = v2[(size_t)n * HID_ + jh * 128 + ct * 16 + l];

    __syncthreads();   // drains the DMA (vmcnt) + the only barrier

    float part[8];
    #pragma unroll
    for (int i = 0; i < 8; ++i) part[i] = 0.f;

    // epilogue x source: row (bh*256 + wave*32 + q*4 + r + rb*16), col (jh*128 + ct*16 + l)
    const size_t xbase = (size_t)(bh * 256 + wave * 32 + q * 4) * HID_ + jh * 128 + l;

    #pragma unroll
    for (int ct = 0; ct < 8; ++ct) {
        // hoist fp32 x loads for the fused epilogue
        float xl[8];
        #pragma unroll
        for (int rb = 0; rb < 2; ++rb)
            #pragma unroll
            for (int r = 0; r < 4; ++r)
                xl[rb * 4 + r] = xp[xbase + (size_t)(rb * 16 + r) * HID_ + ct * 16];

        f32x4 acc0 = {0.f,0.f,0.f,0.f}, acc1 = {0.f,0.f,0.f,0.f};
        #pragma unroll
        for (int kk = 0; kk < 8; ++kk) {
            // swizzled read: row jr=ct*16+l, granule (kk*4+q)^((l&7)<<2)  -> 2-way banks (free)
            const bf16x8 bfrag = *(const bf16x8*)&Ms[(ct * 16 + l) * HID_ +
                                                     (((kk * 4 + q) ^ ((l & 7) << 2)) << 3)];
            acc0 = __builtin_amdgcn_mfma_f32_16x16x32_bf16(afrag[0][kk], bfrag, acc0, 0, 0, 0);
            acc1 = __builtin_amdgcn_mfma_f32_16x16x32_bf16(afrag[1][kk], bfrag, acc1, 0, 0, 0);
        }
        // fused epilogue: part += (T - v2) * x   (C/D layout: col=lane&15, row=quad*4+reg)
        const float vv = v2l[ct];
        #pragma unroll
        for (int r = 0; r < 4; ++r) {
            part[r]     += (acc0[r] - vv) * xl[r];
            part[4 + r] += (acc1[r] - vv) * xl[4 + r];
        }
    }

    // reduce across the 16 col-lanes of each quad
    #pragma unroll
    for (int i = 0; i < 8; ++i) {
        float v = part[i];
        v += __shfl_xor(v, 1);
        v += __shfl_xor(v, 2);
        v += __shfl_xor(v, 4);
        v += __shfl_xor(v, 8);
        part[i] = v;
    }
    if (l == 0) {
        float* pb = p + (size_t)jh * (B_ * N_);
        #pragma unroll
        for (int i = 0; i < 8; ++i) {
            const int row = bh * 256 + wave * 32 + (i >> 2) * 16 + q * 4 + (i & 3);
            pb[(size_t)row * N_ + n] = part[i];
        }
    }
}

// ---------------- finalize: distmat + fused loss gather ----------------
// distmat = sqrt(p0 + p1 + c[n] + 1e-12), written COALESCED; rows with n == labels[b]
// contribute d/B to out[0] via one atomicAdd per wave (out[0] seeded in prep).
__global__ __launch_bounds__(256) void finalize_kernel(
    const float* __restrict__ p, const float* __restrict__ cpart,
    const int* __restrict__ labels, float* __restrict__ out)
{
    __shared__ float sc[128];
    const int t = threadIdx.x;
    if (t < 128) {
        float s = 0.f;
        #pragma unroll
        for (int g = 0; g < 16; ++g) s += cpart[t * 16 + g];
        sc[t] = s;
    }
    __syncthreads();
    const int i = blockIdx.x * 256 + t;             // 0..131071
    const int n = i & (N_ - 1);
    const int b = i >> 7;
    const float d = sqrtf(p[i] + p[B_ * N_ + i] + sc[n] + 1e-12f);
    out[1 + i] = d;
    float c = (labels[b] == n) ? d * (1.f / (float)B_) : 0.f;
    c += __shfl_xor(c, 1);
    c += __shfl_xor(c, 2);
    c += __shfl_xor(c, 4);
    c += __shfl_xor(c, 8);
    c += __shfl_xor(c, 16);
    c += __shfl_xor(c, 32);
    if ((t & 63) == 0 && c != 0.f) atomicAdd(out, c);
}

extern "C" void kernel_launch(void* const* d_in, const int* in_sizes, int n_in,
                              void* d_out, int out_size, void* d_ws, size_t ws_size,
                              hipStream_t stream) {
    const float* x      = (const float*)d_in[0];
    const int*   labels = (const int*)d_in[1];
    const float* W      = (const float*)d_in[2];
    const float* bias   = (const float*)d_in[3];
    const float* means  = (const float*)d_in[4];
    const float* invcov = (const float*)d_in[5];
    float* out = (float*)d_out;

    // workspace carve-up (~19.5 MB total)
    char* ws = (char*)d_ws;
    unsigned short* Mbf   = (unsigned short*)(ws);               // 16,777,216 B
    float*          xp    = (float*)         (ws + 16777216);    //  1,048,576 B
    unsigned short* xbf   = (unsigned short*)(ws + 17825792);    //    524,288 B
    float*          v2    = (float*)         (ws + 18350080);    //    131,072 B
    float*          cpart = (float*)         (ws + 18481152);    //      8,192 B
    float*          p     = (float*)         (ws + 18489344);    //  1,048,576 B

    constexpr int DIST_LDS = 128 * HID_ * 2;   // 65536 B dynamic LDS
    (void)hipFuncSetAttribute((const void*)dist_kernel,
                              hipFuncAttributeMaxDynamicSharedMemorySize, DIST_LDS);

    prep_kernel<<<dim3(2304), 256, 0, stream>>>(x, W, bias, means, invcov,
                                                xp, xbf, Mbf, v2, cpart, out);
    dist_kernel<<<dim3(4, 2, N_), 512, DIST_LDS, stream>>>(xp, xbf, Mbf, v2, p);
    finalize_kernel<<<dim3((B_ * N_) / 256), 256, 0, stream>>>(p, cpart, labels, out);
}